// Round 7
// baseline (149.865 us; speedup 1.0000x reference)
//
#include <hip/hip_runtime.h>
#include <hip/hip_bf16.h>

typedef _Float16 half8 __attribute__((ext_vector_type(8)));
typedef _Float16 half4 __attribute__((ext_vector_type(4)));
typedef _Float16 half2v __attribute__((ext_vector_type(2)));
typedef float f32x4 __attribute__((ext_vector_type(4)));

namespace {

constexpr int INW  = 87;
constexpr int ROWS = 64;    // rows per block
constexpr int NT   = 512;   // 8 waves, each owns a 32-col stripe, all 64 rows

// ws layout (fp16 halves), n-major [256][Kpad], all 16B aligned
constexpr long O_WE  = 0;       // [256][96]: k<77 fold(Wfc1@Wenc), k==77 bias row
constexpr long O_WD  = 24576;   // [256][32]: k<10 fold(Wfc2@Wdec), k==10 bias row
constexpr long O_HDS = 32768;   // 8 x [256][256]
constexpr long O_FC3 = 557056;  // [256][256]
constexpr long CONV_TOTAL = 589824;  // halves for hds+fc3

__device__ __forceinline__ int aidx(int row, int col) {
  return row * 256 + ((((col >> 3) ^ (row & 7)) << 3) | (col & 7));
}

// ---------------- prep: fold enc chain:  WE[n][k] ----------------
__global__ __launch_bounds__(256)
void prep_fold_enc(const float* __restrict__ Wfc1, const float* __restrict__ bfc1,
                   const float* __restrict__ Wenc, const float* __restrict__ benc,
                   _Float16* __restrict__ ws)
{
  const int t = (int)blockIdx.x * 256 + (int)threadIdx.x;   // 96*256 threads
  const int n = t & 255, k = t >> 8;                        // k 0..95
  float acc = 0.f;
  if (k < 77) {
    for (int m = 0; m < 256; ++m) acc += Wfc1[(size_t)k * 256 + m] * Wenc[(size_t)m * 256 + n];
  } else if (k == 77) {
    for (int m = 0; m < 256; ++m) acc += bfc1[m] * Wenc[(size_t)m * 256 + n];
    acc += benc[n];
  }
  ws[O_WE + (long)n * 96 + k] = (_Float16)acc;
}

// ---------------- prep: fold dec chain:  WD[n][k] ----------------
__global__ __launch_bounds__(256)
void prep_fold_dec(const float* __restrict__ Wfc2, const float* __restrict__ bfc2,
                   const float* __restrict__ Wdec, const float* __restrict__ bdec,
                   _Float16* __restrict__ ws)
{
  const int t = (int)blockIdx.x * 256 + (int)threadIdx.x;   // 32*256 threads
  const int n = t & 255, k = t >> 8;                        // k 0..31
  float acc = 0.f;
  if (k < 10) {
    for (int m = 0; m < 256; ++m) acc += Wfc2[(size_t)k * 256 + m] * Wdec[(size_t)m * 256 + n];
  } else if (k == 10) {
    for (int m = 0; m < 256; ++m) acc += bfc2[m] * Wdec[(size_t)m * 256 + n];
    acc += bdec[n];
  }
  ws[O_WD + (long)n * 32 + k] = (_Float16)acc;
}

// ---------------- prep: transpose+convert heads & fc3 ----------------
__global__ __launch_bounds__(256)
void prep_conv(const float* __restrict__ Whds, const float* __restrict__ Wfc3,
               _Float16* __restrict__ ws)
{
  const long t = (long)blockIdx.x * 256 + threadIdx.x;
  const long e = t * 4;
  if (e >= CONV_TOTAL) return;
  const int h = (int)(e >> 16);                 // 0..8 (8 == fc3)
  const float* src = (h < 8) ? (Whds + ((long)h << 16)) : Wfc3;
  const long le = e & 65535;
  const int n = (int)(le >> 8), k0 = (int)(le & 255);
  half4 v;
#pragma unroll
  for (int j = 0; j < 4; ++j)
    v[j] = (_Float16)src[(size_t)(k0 + j) * 256 + n];
  *(half4*)&ws[O_HDS + e] = v;
}

// ---- per-wave barrier-free GEMM: C[64 x 32] += A[64 x K] * W[n][K]^T ----
// B double-buffered in named regs; full unroll gives the scheduler hoist room.
template<int KS>
__device__ __forceinline__ void gemmB(const _Float16* __restrict__ A,
                                      const _Float16* __restrict__ wb, int Klen,
                                      int acol0, int l15, int l4, int cbase,
                                      f32x4 (&acc)[4][2])
{
  const _Float16* b0 = wb + (long)(cbase + l15) * Klen + l4 * 8;
  const _Float16* b1 = b0 + (long)16 * Klen;
  half8 c0 = *(const half8*)b0;
  half8 c1 = *(const half8*)b1;
#pragma unroll
  for (int s = 0; s < KS; ++s) {
    half8 n0, n1;
    if (s + 1 < KS) {
      n0 = *(const half8*)(b0 + (s + 1) * 32);
      n1 = *(const half8*)(b1 + (s + 1) * 32);
    }
    const int acol = acol0 + s * 32;
    half8 af[4];
#pragma unroll
    for (int mt = 0; mt < 4; ++mt) {
      const int row = mt * 16 + l15;
      const int cch = (acol >> 3) + l4;
      af[mt] = *(const half8*)&A[row * 256 + ((cch ^ (row & 7)) << 3)];
    }
#pragma unroll
    for (int mt = 0; mt < 4; ++mt) {
      acc[mt][0] = __builtin_amdgcn_mfma_f32_16x16x32_f16(af[mt], c0, acc[mt][0], 0, 0, 0);
      acc[mt][1] = __builtin_amdgcn_mfma_f32_16x16x32_f16(af[mt], c1, acc[mt][1], 0, 0, 0);
    }
    if (s + 1 < KS) { c0 = n0; c1 = n1; }
  }
}

// =========================== main fused kernel ===========================
__global__ __launch_bounds__(NT)
void fused_mfma(const float* __restrict__ x,
                const float* __restrict__ bhds,
                const float* __restrict__ bfc3,
                const float* __restrict__ Wq,  const float* __restrict__ bq,
                const int* __restrict__ agent,
                const _Float16* __restrict__ ws,
                float* __restrict__ out)
{
  __shared__ _Float16 A[ROWS * 256];        // 32 KB
  __shared__ float sp[2][8][ROWS];          // 4 KB

  const int tid  = (int)threadIdx.x;
  const int lane = tid & 63;
  const int wn   = tid >> 6;        // 0..7 : this wave's 32-col stripe
  const int l15  = lane & 15;
  const int l4   = lane >> 4;
  const int cbase = wn * 32;
  const int row0 = (int)blockIdx.x * ROWS;
  const int a = agent[0];

  auto zeroAcc = [&](f32x4 (&acc)[4][2]) {
#pragma unroll
    for (int mt = 0; mt < 4; ++mt)
#pragma unroll
      for (int nt = 0; nt < 2; ++nt) acc[mt][nt] = { 0.f, 0.f, 0.f, 0.f };
  };

  auto writeA = [&](const f32x4 (&acc)[4][2], bool relu) {
#pragma unroll
    for (int mt = 0; mt < 4; ++mt)
#pragma unroll
      for (int nt = 0; nt < 2; ++nt)
#pragma unroll
        for (int r = 0; r < 4; ++r) {
          float v = acc[mt][nt][r];
          if (relu) v = fmaxf(v, 0.f);
          A[aidx(mt * 16 + l4 * 4 + r, cbase + nt * 16 + l15)] = (_Float16)v;
        }
  };

  // ---- build A0 (cols 0..127): enc-in 0..76, 77=1, dec-others 96..105, 106=1 ----
  for (int i = tid; i < ROWS * 128; i += NT) {
    const int r = i >> 7, c = i & 127;
    float v = 0.f;
    const size_t xb = (size_t)(row0 + r) * INW;
    if (c < 72)            v = x[xb + c];
    else if (c < 77)       v = x[xb + 72 + 5 * a + (c - 72)];
    else if (c == 77)      v = 1.f;
    else if (c >= 96 && c < 106) {
      const int o = c - 96;
      v = x[xb + 72 + (o < 5 * a ? o : o + 5)];
    }
    else if (c == 106)     v = 1.f;
    A[aidx(r, c)] = (_Float16)v;
  }
  __syncthreads();

  // ---- enc_h pre-relu (folded, K=96) ; dec_H pre-relu (folded, K=32) ----
  f32x4 accE[4][2], acc[4][2];
  zeroAcc(accE);
  gemmB<3>(A, ws + O_WE, 96, 0,  l15, l4, cbase, accE);
  zeroAcc(acc);
  gemmB<1>(A, ws + O_WD, 32, 96, l15, l4, cbase, acc);

  half2v dpk[4][2][2];                // dec_H = relu, packed fp16
#pragma unroll
  for (int mt = 0; mt < 4; ++mt)
#pragma unroll
    for (int nt = 0; nt < 2; ++nt)
#pragma unroll
      for (int rh = 0; rh < 2; ++rh)
        dpk[mt][nt][rh] = half2v{
            (_Float16)fmaxf(acc[mt][nt][2 * rh], 0.f),
            (_Float16)fmaxf(acc[mt][nt][2 * rh + 1], 0.f) };

  __syncthreads();                    // all A0 reads done before overwrite
  writeA(accE, true);                 // A := enc_h = relu(...)
  __syncthreads();

  // ---- heads + online softmax (reference = head-0 score) ----
  f32x4 ctx[4][2];
  zeroAcc(ctx);
  float s0[4][4], lsum[4][4];

  for (int h = 0; h < 8; ++h) {
    float bh[2];
#pragma unroll
    for (int nt = 0; nt < 2; ++nt) bh[nt] = bhds[h * 256 + cbase + nt * 16 + l15];

    zeroAcc(acc);
    gemmB<8>(A, ws + O_HDS + (long)h * 65536, 256, 0, l15, l4, cbase, acc);

#pragma unroll
    for (int mt = 0; mt < 4; ++mt)
#pragma unroll
      for (int nt = 0; nt < 2; ++nt)
#pragma unroll
        for (int r = 0; r < 4; ++r)
          acc[mt][nt][r] = fmaxf(acc[mt][nt][r] + bh[nt], 0.f);

    float p[4][4];
#pragma unroll
    for (int mt = 0; mt < 4; ++mt)
#pragma unroll
      for (int r = 0; r < 4; ++r) {
        float v = 0.f;
#pragma unroll
        for (int nt = 0; nt < 2; ++nt)
          v = fmaf(acc[mt][nt][r], (float)dpk[mt][nt][r >> 1][r & 1], v);
        p[mt][r] = v;
      }
#pragma unroll
    for (int off = 1; off < 16; off <<= 1)
#pragma unroll
      for (int mt = 0; mt < 4; ++mt)
#pragma unroll
        for (int r = 0; r < 4; ++r)
          p[mt][r] += __shfl_xor(p[mt][r], off, 64);
    if (l15 == 0) {
#pragma unroll
      for (int mt = 0; mt < 4; ++mt)
#pragma unroll
        for (int r = 0; r < 4; ++r)
          sp[h & 1][wn][mt * 16 + l4 * 4 + r] = p[mt][r];
    }
    __syncthreads();                  // sp[h&1] visible (one barrier per head;
                                      // reuse at h+2 fenced by h+1's barrier)
#pragma unroll
    for (int mt = 0; mt < 4; ++mt)
#pragma unroll
      for (int r = 0; r < 4; ++r) {
        const int row = mt * 16 + l4 * 4 + r;
        float sh = 0.f;
#pragma unroll
        for (int w = 0; w < 8; ++w) sh += sp[h & 1][w][row];
        float wgt;
        if (h == 0) { s0[mt][r] = sh; lsum[mt][r] = 1.f; wgt = 1.f; }
        else {
          wgt = __expf(fminf(sh - s0[mt][r], 70.f));
          lsum[mt][r] += wgt;
        }
#pragma unroll
        for (int nt = 0; nt < 2; ++nt)
          ctx[mt][nt][r] = fmaf(wgt, acc[mt][nt][r], ctx[mt][nt][r]);
      }
  }

#pragma unroll
  for (int mt = 0; mt < 4; ++mt)
#pragma unroll
    for (int r = 0; r < 4; ++r) {
      const float inv = 1.f / lsum[mt][r];
#pragma unroll
      for (int nt = 0; nt < 2; ++nt) ctx[mt][nt][r] *= inv;
    }
  __syncthreads();                    // head-7 A reads done before overwrite
  writeA(ctx, false);                 // A := context
  __syncthreads();

  // ---- fc3 (+bias+relu) then @ Wq ----
  float bf3[2], wq[2];
#pragma unroll
  for (int nt = 0; nt < 2; ++nt) {
    bf3[nt] = bfc3[cbase + nt * 16 + l15];
    wq[nt]  = Wq[cbase + nt * 16 + l15];
  }
  zeroAcc(acc);
  gemmB<8>(A, ws + O_FC3, 256, 0, l15, l4, cbase, acc);

  float p[4][4];
#pragma unroll
  for (int mt = 0; mt < 4; ++mt)
#pragma unroll
    for (int r = 0; r < 4; ++r) {
      float v = 0.f;
#pragma unroll
      for (int nt = 0; nt < 2; ++nt)
        v = fmaf(fmaxf(acc[mt][nt][r] + bf3[nt], 0.f), wq[nt], v);
      p[mt][r] = v;
    }
#pragma unroll
  for (int off = 1; off < 16; off <<= 1)
#pragma unroll
    for (int mt = 0; mt < 4; ++mt)
#pragma unroll
      for (int r = 0; r < 4; ++r)
        p[mt][r] += __shfl_xor(p[mt][r], off, 64);
  if (l15 == 0) {
#pragma unroll
    for (int mt = 0; mt < 4; ++mt)
#pragma unroll
      for (int r = 0; r < 4; ++r)
        sp[0][wn][mt * 16 + l4 * 4 + r] = p[mt][r];
  }
  __syncthreads();
  if (tid < ROWS) {
    float v = bq[0];
#pragma unroll
    for (int w = 0; w < 8; ++w) v += sp[0][w][tid];
    out[row0 + tid] = v;
  }
}

}  // namespace

extern "C" void kernel_launch(void* const* d_in, const int* in_sizes, int n_in,
                              void* d_out, int out_size, void* d_ws, size_t ws_size,
                              hipStream_t stream) {
  const float* x    = (const float*)d_in[0];
  const float* Wfc1 = (const float*)d_in[1];
  const float* bfc1 = (const float*)d_in[2];
  const float* Wfc2 = (const float*)d_in[3];
  const float* bfc2 = (const float*)d_in[4];
  const float* Wenc = (const float*)d_in[5];
  const float* benc = (const float*)d_in[6];
  const float* Whds = (const float*)d_in[7];
  const float* bhds = (const float*)d_in[8];
  const float* Wdec = (const float*)d_in[9];
  const float* bdec = (const float*)d_in[10];
  const float* Wfc3 = (const float*)d_in[11];
  const float* bfc3 = (const float*)d_in[12];
  const float* Wq   = (const float*)d_in[13];
  const float* bq   = (const float*)d_in[14];
  const int*  agent = (const int*)d_in[15];
  float* out = (float*)d_out;
  _Float16* ws = (_Float16*)d_ws;

  const int Bn = in_sizes[0] / INW;         // 32768
  const int grid = Bn / ROWS;               // 512 blocks

  prep_fold_enc<<<96, 256, 0, stream>>>(Wfc1, bfc1, Wenc, benc, ws);
  prep_fold_dec<<<32, 256, 0, stream>>>(Wfc2, bfc2, Wdec, bdec, ws);
  prep_conv<<<(int)((CONV_TOTAL / 4 + 255) / 256), 256, 0, stream>>>(Whds, Wfc3, ws);
  fused_mfma<<<grid, NT, 0, stream>>>(x, bhds, bfc3, Wq, bq, agent, ws, out);
}

// Round 8
// 123.873 us; speedup vs baseline: 1.2098x; 1.2098x over previous
//
#include <hip/hip_runtime.h>
#include <hip/hip_bf16.h>

typedef _Float16 half8 __attribute__((ext_vector_type(8)));
typedef _Float16 half4 __attribute__((ext_vector_type(4)));
typedef _Float16 half2v __attribute__((ext_vector_type(2)));
typedef float f32x4 __attribute__((ext_vector_type(4)));

namespace {

constexpr int INW  = 87;
constexpr int ROWS = 64;    // rows per block
constexpr int NT   = 512;   // 8 waves, each owns a 32-col stripe, all 64 rows

// ws layout (fp16 halves), n-major [256][Kpad], all 16B aligned
constexpr long O_WE  = 0;       // [256][96]: k<77 fold(Wfc1@Wenc), k==77 bias row
constexpr long O_WD  = 24576;   // [256][32]: k<10 fold(Wfc2@Wdec), k==10 bias row
constexpr long O_HDS = 32768;   // 8 x [256][256]
constexpr long O_FC3 = 557056;  // [256][256]
constexpr long CONV_TOTAL = 589824;  // halves for hds+fc3

__device__ __forceinline__ int aidx(int row, int col) {
  return row * 256 + ((((col >> 3) ^ (row & 7)) << 3) | (col & 7));
}

// ---------------- prep: fold enc chain:  WE[n][k] ----------------
__global__ __launch_bounds__(256)
void prep_fold_enc(const float* __restrict__ Wfc1, const float* __restrict__ bfc1,
                   const float* __restrict__ Wenc, const float* __restrict__ benc,
                   _Float16* __restrict__ ws)
{
  const int t = (int)blockIdx.x * 256 + (int)threadIdx.x;   // 96*256 threads
  const int n = t & 255, k = t >> 8;                        // k 0..95
  float acc = 0.f;
  if (k < 77) {
    for (int m = 0; m < 256; ++m) acc += Wfc1[(size_t)k * 256 + m] * Wenc[(size_t)m * 256 + n];
  } else if (k == 77) {
    for (int m = 0; m < 256; ++m) acc += bfc1[m] * Wenc[(size_t)m * 256 + n];
    acc += benc[n];
  }
  ws[O_WE + (long)n * 96 + k] = (_Float16)acc;
}

// ---------------- prep: fold dec chain:  WD[n][k] ----------------
__global__ __launch_bounds__(256)
void prep_fold_dec(const float* __restrict__ Wfc2, const float* __restrict__ bfc2,
                   const float* __restrict__ Wdec, const float* __restrict__ bdec,
                   _Float16* __restrict__ ws)
{
  const int t = (int)blockIdx.x * 256 + (int)threadIdx.x;   // 32*256 threads
  const int n = t & 255, k = t >> 8;                        // k 0..31
  float acc = 0.f;
  if (k < 10) {
    for (int m = 0; m < 256; ++m) acc += Wfc2[(size_t)k * 256 + m] * Wdec[(size_t)m * 256 + n];
  } else if (k == 10) {
    for (int m = 0; m < 256; ++m) acc += bfc2[m] * Wdec[(size_t)m * 256 + n];
    acc += bdec[n];
  }
  ws[O_WD + (long)n * 32 + k] = (_Float16)acc;
}

// ---------------- prep: transpose+convert heads & fc3 ----------------
__global__ __launch_bounds__(256)
void prep_conv(const float* __restrict__ Whds, const float* __restrict__ Wfc3,
               _Float16* __restrict__ ws)
{
  const long t = (long)blockIdx.x * 256 + threadIdx.x;
  const long e = t * 4;
  if (e >= CONV_TOTAL) return;
  const int h = (int)(e >> 16);                 // 0..8 (8 == fc3)
  const float* src = (h < 8) ? (Whds + ((long)h << 16)) : Wfc3;
  const long le = e & 65535;
  const int n = (int)(le >> 8), k0 = (int)(le & 255);
  half4 v;
#pragma unroll
  for (int j = 0; j < 4; ++j)
    v[j] = (_Float16)src[(size_t)(k0 + j) * 256 + n];
  *(half4*)&ws[O_HDS + e] = v;
}

// lgkm-only barrier: LDS visibility without draining vmcnt (B prefetches
// stay in flight across it).
__device__ __forceinline__ void sync_lgkm() {
  asm volatile("s_waitcnt lgkmcnt(0)" ::: "memory");
  __builtin_amdgcn_s_barrier();
}

struct SliceD { const _Float16* base; int Klen; int k0; };
__device__ __forceinline__ SliceD slice_desc(int i, const _Float16* ws) {
  if (i < 3)  return { ws + O_WE, 96, i * 32 };
  if (i == 3) return { ws + O_WD, 32, 0 };
  if (i < 68) { const int t = i - 4;
                return { ws + O_HDS + (long)(t >> 3) * 65536, 256, (t & 7) * 32 }; }
  return { ws + O_FC3, 256, (i - 68) * 32 };
}

// =========================== main fused kernel ===========================
__global__ __launch_bounds__(NT)
void fused_mfma(const float* __restrict__ x,
                const float* __restrict__ bhds,
                const float* __restrict__ bfc3,
                const float* __restrict__ Wq,  const float* __restrict__ bq,
                const int* __restrict__ agent,
                const _Float16* __restrict__ ws,
                float* __restrict__ out)
{
  __shared__ _Float16 A[ROWS * 256];        // 32 KB
  __shared__ float sp[2][8][ROWS];          // 4 KB

  const int tid  = (int)threadIdx.x;
  const int lane = tid & 63;
  const int wn   = tid >> 6;        // 0..7 : this wave's 32-col stripe
  const int l15  = lane & 15;
  const int l4   = lane >> 4;
  const int cbase = wn * 32;
  const int row0 = (int)blockIdx.x * ROWS;
  const int a = agent[0];

  auto loadB = [&](int i, half8& qa, half8& qb) {
    const SliceD d = slice_desc(i, ws);
    const _Float16* p = d.base + (long)(cbase + l15) * d.Klen + d.k0 + (long)l4 * 8;
    qa = *(const half8*)p;
    qb = *(const half8*)(p + (long)16 * d.Klen);
  };
  auto ldAF = [&](half8 (&af)[4], int acol) {
#pragma unroll
    for (int mt = 0; mt < 4; ++mt) {
      const int row = mt * 16 + l15;
      const int cch = (acol >> 3) + l4;
      af[mt] = *(const half8*)&A[row * 256 + ((cch ^ (row & 7)) << 3)];
    }
  };
  auto mfma8 = [&](const half8 (&af)[4], const half8& ba, const half8& bb,
                   f32x4 (&acc)[4][2]) {
#pragma unroll
    for (int mt = 0; mt < 4; ++mt) {
      acc[mt][0] = __builtin_amdgcn_mfma_f32_16x16x32_f16(af[mt], ba, acc[mt][0], 0, 0, 0);
      acc[mt][1] = __builtin_amdgcn_mfma_f32_16x16x32_f16(af[mt], bb, acc[mt][1], 0, 0, 0);
    }
  };
  auto zeroAcc = [&](f32x4 (&acc)[4][2]) {
#pragma unroll
    for (int mt = 0; mt < 4; ++mt)
#pragma unroll
      for (int nt = 0; nt < 2; ++nt) acc[mt][nt] = { 0.f, 0.f, 0.f, 0.f };
  };
  auto writeA = [&](const f32x4 (&acc)[4][2], bool relu) {
#pragma unroll
    for (int mt = 0; mt < 4; ++mt)
#pragma unroll
      for (int nt = 0; nt < 2; ++nt)
#pragma unroll
        for (int r = 0; r < 4; ++r) {
          float v = acc[mt][nt][r];
          if (relu) v = fmaxf(v, 0.f);
          A[aidx(mt * 16 + l4 * 4 + r, cbase + nt * 16 + l15)] = (_Float16)v;
        }
  };

  // ---- issue first 4 B slices (depth-4 pipeline prologue) ----
  half8 q0a, q0b, q1a, q1b, q2a, q2b, q3a, q3b;
  loadB(0, q0a, q0b); loadB(1, q1a, q1b);
  loadB(2, q2a, q2b); loadB(3, q3a, q3b);

  // ---- build A0 (cols 0..127): enc-in 0..76, 77=1, dec-others 96..105, 106=1 ----
  for (int i = tid; i < ROWS * 128; i += NT) {
    const int r = i >> 7, c = i & 127;
    float v = 0.f;
    const size_t xb = (size_t)(row0 + r) * INW;
    if (c < 72)            v = x[xb + c];
    else if (c < 77)       v = x[xb + 72 + 5 * a + (c - 72)];
    else if (c == 77)      v = 1.f;
    else if (c >= 96 && c < 106) {
      const int o = c - 96;
      v = x[xb + 72 + (o < 5 * a ? o : o + 5)];
    }
    else if (c == 106)     v = 1.f;
    A[aidx(r, c)] = (_Float16)v;
  }
  sync_lgkm();

  // ---- enc_h pre-relu (K=96) ; dec_H pre-relu (K=32) ----
  f32x4 accE[4][2], accD[4][2], acc[4][2];
  zeroAcc(accE); zeroAcc(accD);
  {
    half8 af[4];
    ldAF(af, 0);  mfma8(af, q0a, q0b, accE); loadB(4, q0a, q0b);
    ldAF(af, 32); mfma8(af, q1a, q1b, accE); loadB(5, q1a, q1b);
    ldAF(af, 64); mfma8(af, q2a, q2b, accE); loadB(6, q2a, q2b);
    ldAF(af, 96); mfma8(af, q3a, q3b, accD); loadB(7, q3a, q3b);
  }

  half2v dpk[4][2][2];                // dec_H = relu, packed fp16
#pragma unroll
  for (int mt = 0; mt < 4; ++mt)
#pragma unroll
    for (int nt = 0; nt < 2; ++nt)
#pragma unroll
      for (int rh = 0; rh < 2; ++rh)
        dpk[mt][nt][rh] = half2v{
            (_Float16)fmaxf(accD[mt][nt][2 * rh], 0.f),
            (_Float16)fmaxf(accD[mt][nt][2 * rh + 1], 0.f) };

  sync_lgkm();                        // A0 reads done (consumed by MFMAs above)
  writeA(accE, true);                 // A := enc_h = relu(...)
  sync_lgkm();

  // ---- heads + online softmax; softmax state lives at row==lane ----
  f32x4 ctx[4][2];
  zeroAcc(ctx);
  float s0L = 0.f, lsumL = 1.f;       // for row == lane

  half8 afC[4], afN[4];
  ldAF(afC, 0);

  for (int h = 0; h < 8; ++h) {
    const int base = 4 + 8 * h;
    float bh[2];
#pragma unroll
    for (int nt = 0; nt < 2; ++nt) bh[nt] = bhds[h * 256 + cbase + nt * 16 + l15];

    zeroAcc(acc);
    ldAF(afN, 32);  mfma8(afC, q0a, q0b, acc); loadB(base + 4,  q0a, q0b);
    ldAF(afC, 64);  mfma8(afN, q1a, q1b, acc); loadB(base + 5,  q1a, q1b);
    ldAF(afN, 96);  mfma8(afC, q2a, q2b, acc); loadB(base + 6,  q2a, q2b);
    ldAF(afC, 128); mfma8(afN, q3a, q3b, acc); loadB(base + 7,  q3a, q3b);
    ldAF(afN, 160); mfma8(afC, q0a, q0b, acc); loadB(base + 8,  q0a, q0b);
    ldAF(afC, 192); mfma8(afN, q1a, q1b, acc); loadB(base + 9,  q1a, q1b);
    ldAF(afN, 224); mfma8(afC, q2a, q2b, acc); loadB(base + 10, q2a, q2b);
    ldAF(afC, 0);   mfma8(afN, q3a, q3b, acc); loadB(base + 11, q3a, q3b);

#pragma unroll
    for (int mt = 0; mt < 4; ++mt)
#pragma unroll
      for (int nt = 0; nt < 2; ++nt)
#pragma unroll
        for (int r = 0; r < 4; ++r)
          acc[mt][nt][r] = fmaxf(acc[mt][nt][r] + bh[nt], 0.f);

    // score partials over this wave's 32 cols
    float p[4][4];
#pragma unroll
    for (int mt = 0; mt < 4; ++mt)
#pragma unroll
      for (int r = 0; r < 4; ++r) {
        float v = 0.f;
#pragma unroll
        for (int nt = 0; nt < 2; ++nt)
          v = fmaf(acc[mt][nt][r], (float)dpk[mt][nt][r >> 1][r & 1], v);
        p[mt][r] = v;
      }
#pragma unroll
    for (int off = 1; off < 16; off <<= 1)
#pragma unroll
      for (int mt = 0; mt < 4; ++mt)
#pragma unroll
        for (int r = 0; r < 4; ++r)
          p[mt][r] += __shfl_xor(p[mt][r], off, 64);
    if (l15 == 0) {
#pragma unroll
      for (int mt = 0; mt < 4; ++mt)
#pragma unroll
        for (int r = 0; r < 4; ++r)
          sp[h & 1][wn][mt * 16 + l4 * 4 + r] = p[mt][r];
    }
    sync_lgkm();                      // sp[h&1] visible; B loads stay in flight

    // total score for row == lane (8 scalar LDS reads), softmax update
    float sh = 0.f;
#pragma unroll
    for (int w = 0; w < 8; ++w) sh += sp[h & 1][w][lane];
    float wL;
    if (h == 0) { s0L = sh; lsumL = 1.f; wL = 1.f; }
    else        { wL = __expf(fminf(sh - s0L, 70.f)); lsumL += wL; }

    // redistribute weight to the (mt,r) holders of each row
#pragma unroll
    for (int mt = 0; mt < 4; ++mt)
#pragma unroll
      for (int r = 0; r < 4; ++r) {
        const float wgt = __shfl(wL, mt * 16 + l4 * 4 + r, 64);
#pragma unroll
        for (int nt = 0; nt < 2; ++nt)
          ctx[mt][nt][r] = fmaf(wgt, acc[mt][nt][r], ctx[mt][nt][r]);
      }
    // sp[h&1] reused at h+2; fenced by head h+1's barrier
  }

  // normalize context (inv at row==lane, shfl out)
  {
    const float invL = 1.f / lsumL;
#pragma unroll
    for (int mt = 0; mt < 4; ++mt)
#pragma unroll
      for (int r = 0; r < 4; ++r) {
        const float inv = __shfl(invL, mt * 16 + l4 * 4 + r, 64);
#pragma unroll
        for (int nt = 0; nt < 2; ++nt) ctx[mt][nt][r] *= inv;
      }
  }
  sync_lgkm();                        // head-7 A reads done
  writeA(ctx, false);                 // A := context
  sync_lgkm();

  // ---- fc3 (+bias+relu) then @ Wq ----
  float bf3[2], wq[2];
#pragma unroll
  for (int nt = 0; nt < 2; ++nt) {
    bf3[nt] = bfc3[cbase + nt * 16 + l15];
    wq[nt]  = Wq[cbase + nt * 16 + l15];
  }
  zeroAcc(acc);
  ldAF(afC, 0);
  ldAF(afN, 32);  mfma8(afC, q0a, q0b, acc); loadB(72, q0a, q0b);
  ldAF(afC, 64);  mfma8(afN, q1a, q1b, acc); loadB(73, q1a, q1b);
  ldAF(afN, 96);  mfma8(afC, q2a, q2b, acc); loadB(74, q2a, q2b);
  ldAF(afC, 128); mfma8(afN, q3a, q3b, acc); loadB(75, q3a, q3b);
  ldAF(afN, 160); mfma8(afC, q0a, q0b, acc);
  ldAF(afC, 192); mfma8(afN, q1a, q1b, acc);
  ldAF(afN, 224); mfma8(afC, q2a, q2b, acc);
                  mfma8(afN, q3a, q3b, acc);

  float p[4][4];
#pragma unroll
  for (int mt = 0; mt < 4; ++mt)
#pragma unroll
    for (int r = 0; r < 4; ++r) {
      float v = 0.f;
#pragma unroll
      for (int nt = 0; nt < 2; ++nt)
        v = fmaf(fmaxf(acc[mt][nt][r] + bf3[nt], 0.f), wq[nt], v);
      p[mt][r] = v;
    }
#pragma unroll
  for (int off = 1; off < 16; off <<= 1)
#pragma unroll
    for (int mt = 0; mt < 4; ++mt)
#pragma unroll
      for (int r = 0; r < 4; ++r)
        p[mt][r] += __shfl_xor(p[mt][r], off, 64);
  if (l15 == 0) {
#pragma unroll
    for (int mt = 0; mt < 4; ++mt)
#pragma unroll
      for (int r = 0; r < 4; ++r)
        sp[0][wn][mt * 16 + l4 * 4 + r] = p[mt][r];
  }
  sync_lgkm();
  if (tid < ROWS) {
    float v = bq[0];
#pragma unroll
    for (int w = 0; w < 8; ++w) v += sp[0][w][tid];
    out[row0 + tid] = v;
  }
}

}  // namespace

extern "C" void kernel_launch(void* const* d_in, const int* in_sizes, int n_in,
                              void* d_out, int out_size, void* d_ws, size_t ws_size,
                              hipStream_t stream) {
  const float* x    = (const float*)d_in[0];
  const float* Wfc1 = (const float*)d_in[1];
  const float* bfc1 = (const float*)d_in[2];
  const float* Wfc2 = (const float*)d_in[3];
  const float* bfc2 = (const float*)d_in[4];
  const float* Wenc = (const float*)d_in[5];
  const float* benc = (const float*)d_in[6];
  const float* Whds = (const float*)d_in[7];
  const float* bhds = (const float*)d_in[8];
  const float* Wdec = (const float*)d_in[9];
  const float* bdec = (const float*)d_in[10];
  const float* Wfc3 = (const float*)d_in[11];
  const float* bfc3 = (const float*)d_in[12];
  const float* Wq   = (const float*)d_in[13];
  const float* bq   = (const float*)d_in[14];
  const int*  agent = (const int*)d_in[15];
  float* out = (float*)d_out;
  _Float16* ws = (_Float16*)d_ws;

  const int Bn = in_sizes[0] / INW;         // 32768
  const int grid = Bn / ROWS;               // 512 blocks

  prep_fold_enc<<<96, 256, 0, stream>>>(Wfc1, bfc1, Wenc, benc, ws);
  prep_fold_dec<<<32, 256, 0, stream>>>(Wfc2, bfc2, Wdec, bdec, ws);
  prep_conv<<<(int)((CONV_TOTAL / 4 + 255) / 256), 256, 0, stream>>>(Whds, Wfc3, ws);
  fused_mfma<<<grid, NT, 0, stream>>>(x, bhds, bfc3, Wq, bq, agent, ws, out);
}